// Round 2
// baseline (1071.407 us; speedup 1.0000x reference)
//
#include <hip/hip_runtime.h>

typedef __attribute__((ext_vector_type(8))) short short8;
typedef __attribute__((ext_vector_type(4))) short short4v;
typedef __attribute__((ext_vector_type(4))) float float4v;

#define N_EDGES 640000

// RNE float -> bf16 (as raw short)
__device__ __forceinline__ short f2bf(float f) {
  union { float f; unsigned u; } a; a.f = f;
  unsigned r = a.u + 0x7FFFu + ((a.u >> 16) & 1u);
  return (short)(r >> 16);
}

__device__ __forceinline__ float fast_tanh(float x) {
  float xc = fminf(fmaxf(x, -15.f), 15.f);
  float e = __expf(2.f * xc);
  return (e - 1.f) * __builtin_amdgcn_rcpf(e + 1.f);
}

// ws layout (shorts): U[0,16384) V[16384,32768) M1[32768,49152)
//                     W1b[49152,65536) W2[65536,81920)
// b1p (f32[128]) at short offset 81920 (byte 163840).

// Straight conversions: U, V, W1b (= cols 128..255 of W1), W2.
__global__ void prep_cvt(const float* __restrict__ U_w, const float* __restrict__ V_w,
                         const float* __restrict__ W1, const float* __restrict__ W2,
                         short* __restrict__ ws) {
  int i = blockIdx.x * 256 + threadIdx.x;   // 65536 total
  if (i < 16384) {
    ws[i] = f2bf(U_w[i]);
  } else if (i < 32768) {
    ws[i] = f2bf(V_w[i - 16384]);
  } else if (i < 49152) {
    int j = i - 32768;                       // W1b[o][k] = W1[o][128+k]
    ws[i + 16384] = f2bf(W1[(j >> 7) * 256 + 128 + (j & 127)]);
  } else {
    int j = i - 49152;
    ws[i + 16384] = f2bf(W2[j]);
  }
}

// M1 = W1a @ P_w  (M1[o][k] = sum_c W1[o][c] * P_w[c][k]), bf16.
// b1p = b1 + W1a @ P_b, f32.
__global__ void prep_mm(const float* __restrict__ W1, const float* __restrict__ P_w,
                        const float* __restrict__ P_b, const float* __restrict__ b1,
                        short* __restrict__ ws) {
  int i = blockIdx.x * 256 + threadIdx.x;   // 16384 total
  int o = i >> 7, k = i & 127;
  const float* wrow = W1 + o * 256;         // W1a row o
  const float* pcol = P_w + k;
  float a0 = 0.f, a1 = 0.f, a2 = 0.f, a3 = 0.f;
#pragma unroll
  for (int c = 0; c < 128; c += 4) {
    a0 += wrow[c]     * pcol[c * 128];
    a1 += wrow[c + 1] * pcol[(c + 1) * 128];
    a2 += wrow[c + 2] * pcol[(c + 2) * 128];
    a3 += wrow[c + 3] * pcol[(c + 3) * 128];
  }
  ws[32768 + i] = f2bf((a0 + a1) + (a2 + a3));
  if (i < 128) {
    const float* wr = W1 + i * 256;
    float b = b1[i];
    for (int c = 0; c < 128; c++) b += wr[c] * P_b[c];
    ((float*)ws)[81920 / 2] = ((float*)ws)[81920 / 2];  // keep alignment obvious
    ((float*)(ws + 81920))[i] = b;
  }
}

// Block = 64 edges. 4 waves split N (2 n-tiles each). 2 LDS buffers -> 4 blocks/CU.
//   bufA: Vsrc -> t          bufB: Vdst -> h1
// Stage 2 (pooled) is algebraically folded into stage 3 via M1 = W1a@P.
// Ea is read directly from global f32 inside stage 3 (leaky+cvt in regs).
__global__ __launch_bounds__(256, 4) void fused_kernel(
    const float* __restrict__ V, const float* __restrict__ E,
    const int* __restrict__ src, const int* __restrict__ dst,
    const short* __restrict__ wbf,
    const float* __restrict__ b2, float* __restrict__ out) {
  __shared__ short bufA[64][136];
  __shared__ short bufB[64][136];

  const int tid  = threadIdx.x;
  const int lane = tid & 63;
  const int wave = tid >> 6;
  const int l15  = lane & 15;
  const int quad = lane >> 4;
  const int eb   = blockIdx.x * 64;
  const int n0   = wave * 2;            // this wave's first n-tile

  const short* wU   = wbf;
  const short* wV   = wbf + 16384;
  const short* wM1  = wbf + 32768;
  const short* wW1b = wbf + 49152;
  const short* wW2  = wbf + 65536;
  const float* b1p  = (const float*)(wbf + 81920);

  // biases for this wave's output columns
  float b1v[2], b2v[2];
#pragma unroll
  for (int n = 0; n < 2; n++) {
    int c = (n0 + n) * 16 + l15;
    b1v[n] = b1p[c]; b2v[n] = b2[c];
  }

  // ---------- staging: gather V[src], V[dst] -> LDS bf16 ----------
  for (int i = tid; i < 2048; i += 256) {   // 64 rows * 32 float4-chunks
    int row = i >> 5;
    int ch  = i & 31;
    int e   = eb + row;
    int s = src[e], d = dst[e];
    float4v vs = *((const float4v*)(V + (size_t)s * 128) + ch);
    float4v vd = *((const float4v*)(V + (size_t)d * 128) + ch);
    short4v ps = {f2bf(vs[0]), f2bf(vs[1]), f2bf(vs[2]), f2bf(vs[3])};
    short4v pd = {f2bf(vd[0]), f2bf(vd[1]), f2bf(vd[2]), f2bf(vd[3])};
    *(short4v*)&bufA[row][ch * 4] = ps;
    *(short4v*)&bufB[row][ch * 4] = pd;
  }
  __syncthreads();

  // ---------- stage 1: h_s = Vs @ U^T, h_d = Vd @ Vw^T (acc in regs) ----------
  float4v accS[4][2], accD[4][2];
#pragma unroll
  for (int m = 0; m < 4; m++)
#pragma unroll
    for (int n = 0; n < 2; n++) {
      accS[m][n] = (float4v){0.f, 0.f, 0.f, 0.f};
      accD[m][n] = (float4v){0.f, 0.f, 0.f, 0.f};
    }
#pragma unroll
  for (int kk = 0; kk < 4; kk++) {
    short8 bU[2], bV[2];
#pragma unroll
    for (int n = 0; n < 2; n++) {
      const int off = ((n0 + n) * 16 + l15) * 128 + kk * 32 + quad * 8;
      bU[n] = *(const short8*)(wU + off);
      bV[n] = *(const short8*)(wV + off);
    }
#pragma unroll
    for (int m = 0; m < 4; m++) {
      short8 aS = *(const short8*)&bufA[m * 16 + l15][kk * 32 + quad * 8];
      short8 aD = *(const short8*)&bufB[m * 16 + l15][kk * 32 + quad * 8];
#pragma unroll
      for (int n = 0; n < 2; n++) {
        accS[m][n] = __builtin_amdgcn_mfma_f32_16x16x32_bf16(aS, bU[n], accS[m][n], 0, 0, 0);
        accD[m][n] = __builtin_amdgcn_mfma_f32_16x16x32_bf16(aD, bV[n], accD[m][n], 0, 0, 0);
      }
    }
  }
  __syncthreads();   // all stage-1 LDS reads done; bufA and bufB both free

  // t = tanh(h_s * h_d) -> bufA (transpose through LDS)
#pragma unroll
  for (int m = 0; m < 4; m++)
#pragma unroll
    for (int n = 0; n < 2; n++)
#pragma unroll
      for (int r = 0; r < 4; r++) {
        float t = fast_tanh(accS[m][n][r] * accD[m][n][r]);
        bufA[m * 16 + quad * 4 + r][(n0 + n) * 16 + l15] = f2bf(t);
      }
  __syncthreads();

  // ---------- stage 3': h1 = relu(t @ M1^T + Ea @ W1b^T + b1') -> bufB ----------
#pragma unroll
  for (int m = 0; m < 4; m++) {
    // issue E loads for this m-tile early (f32, 32B per kk-fragment)
    const float* erow = E + (size_t)(eb + m * 16 + l15) * 128;
    float4v ef[8];
#pragma unroll
    for (int kk = 0; kk < 4; kk++) {
      ef[kk * 2]     = *((const float4v*)erow + kk * 8 + quad * 2);
      ef[kk * 2 + 1] = *((const float4v*)erow + kk * 8 + quad * 2 + 1);
    }
    float4v acc[2] = {(float4v){0.f,0.f,0.f,0.f}, (float4v){0.f,0.f,0.f,0.f}};
    // K-half A: t @ M1 (hides the E-load latency)
#pragma unroll
    for (int kk = 0; kk < 4; kk++) {
      short8 bM[2];
#pragma unroll
      for (int n = 0; n < 2; n++)
        bM[n] = *(const short8*)(wM1 + ((n0 + n) * 16 + l15) * 128 + kk * 32 + quad * 8);
      short8 a = *(const short8*)&bufA[m * 16 + l15][kk * 32 + quad * 8];
#pragma unroll
      for (int n = 0; n < 2; n++)
        acc[n] = __builtin_amdgcn_mfma_f32_16x16x32_bf16(a, bM[n], acc[n], 0, 0, 0);
    }
    // convert E fragments: leaky + bf16
    short8 efr[4];
#pragma unroll
    for (int kk = 0; kk < 4; kk++) {
      float4v x = ef[kk * 2], y = ef[kk * 2 + 1];
      float e0 = x[0] > 0.f ? x[0] : 0.01f * x[0];
      float e1 = x[1] > 0.f ? x[1] : 0.01f * x[1];
      float e2 = x[2] > 0.f ? x[2] : 0.01f * x[2];
      float e3 = x[3] > 0.f ? x[3] : 0.01f * x[3];
      float e4 = y[0] > 0.f ? y[0] : 0.01f * y[0];
      float e5 = y[1] > 0.f ? y[1] : 0.01f * y[1];
      float e6 = y[2] > 0.f ? y[2] : 0.01f * y[2];
      float e7 = y[3] > 0.f ? y[3] : 0.01f * y[3];
      efr[kk] = (short8){f2bf(e0), f2bf(e1), f2bf(e2), f2bf(e3),
                         f2bf(e4), f2bf(e5), f2bf(e6), f2bf(e7)};
    }
    // K-half B: Ea @ W1b
#pragma unroll
    for (int kk = 0; kk < 4; kk++) {
      short8 bW[2];
#pragma unroll
      for (int n = 0; n < 2; n++)
        bW[n] = *(const short8*)(wW1b + ((n0 + n) * 16 + l15) * 128 + kk * 32 + quad * 8);
#pragma unroll
      for (int n = 0; n < 2; n++)
        acc[n] = __builtin_amdgcn_mfma_f32_16x16x32_bf16(efr[kk], bW[n], acc[n], 0, 0, 0);
    }
    // h1 -> bufB (bufB is dead since stage 1; each wave owns its columns)
#pragma unroll
    for (int n = 0; n < 2; n++)
#pragma unroll
      for (int r = 0; r < 4; r++) {
        float v = fmaxf(acc[n][r] + b1v[n], 0.f);
        bufB[m * 16 + quad * 4 + r][(n0 + n) * 16 + l15] = f2bf(v);
      }
  }
  __syncthreads();

  // ---------- stage 4: out = relu(h1 @ W2^T + b2) -> global ----------
  {
    float4v accO[4][2];
#pragma unroll
    for (int m = 0; m < 4; m++)
#pragma unroll
      for (int n = 0; n < 2; n++) accO[m][n] = (float4v){0.f, 0.f, 0.f, 0.f};
#pragma unroll
    for (int kk = 0; kk < 4; kk++) {
      short8 bW[2];
#pragma unroll
      for (int n = 0; n < 2; n++)
        bW[n] = *(const short8*)(wW2 + ((n0 + n) * 16 + l15) * 128 + kk * 32 + quad * 8);
#pragma unroll
      for (int m = 0; m < 4; m++) {
        short8 a = *(const short8*)&bufB[m * 16 + l15][kk * 32 + quad * 8];
#pragma unroll
        for (int n = 0; n < 2; n++)
          accO[m][n] = __builtin_amdgcn_mfma_f32_16x16x32_bf16(a, bW[n], accO[m][n], 0, 0, 0);
      }
    }
#pragma unroll
    for (int m = 0; m < 4; m++)
#pragma unroll
      for (int n = 0; n < 2; n++)
#pragma unroll
        for (int r = 0; r < 4; r++) {
          float v = fmaxf(accO[m][n][r] + b2v[n], 0.f);
          __builtin_nontemporal_store(
              v, out + (size_t)(eb + m * 16 + quad * 4 + r) * 128 + (n0 + n) * 16 + l15);
        }
  }
}

extern "C" void kernel_launch(void* const* d_in, const int* in_sizes, int n_in,
                              void* d_out, int out_size, void* d_ws, size_t ws_size,
                              hipStream_t stream) {
  const float* V   = (const float*)d_in[0];
  const float* E   = (const float*)d_in[1];
  const int*   src = (const int*)d_in[2];
  const int*   dst = (const int*)d_in[3];
  const float* U_w = (const float*)d_in[4];
  const float* V_w = (const float*)d_in[5];
  const float* P_w = (const float*)d_in[6];
  const float* P_b = (const float*)d_in[7];
  const float* W1  = (const float*)d_in[8];
  const float* b1  = (const float*)d_in[9];
  const float* W2  = (const float*)d_in[10];
  const float* b2  = (const float*)d_in[11];
  short* ws = (short*)d_ws;

  hipLaunchKernelGGL(prep_cvt, dim3(256), dim3(256), 0, stream, U_w, V_w, W1, W2, ws);
  hipLaunchKernelGGL(prep_mm, dim3(64), dim3(256), 0, stream, W1, P_w, P_b, b1, ws);
  hipLaunchKernelGGL(fused_kernel, dim3(N_EDGES / 64), dim3(256), 0, stream,
                     V, E, src, dst, ws, b2, (float*)d_out);
}

// Round 3
// 775.045 us; speedup vs baseline: 1.3824x; 1.3824x over previous
//
#include <hip/hip_runtime.h>

typedef __attribute__((ext_vector_type(8))) short short8;
typedef __attribute__((ext_vector_type(4))) short short4v;
typedef __attribute__((ext_vector_type(4))) float float4v;

#define N_EDGES 640000

// RNE float -> bf16 (as raw short)
__device__ __forceinline__ short f2bf(float f) {
  union { float f; unsigned u; } a; a.f = f;
  unsigned r = a.u + 0x7FFFu + ((a.u >> 16) & 1u);
  return (short)(r >> 16);
}

__device__ __forceinline__ float fast_tanh(float x) {
  float xc = fminf(fmaxf(x, -15.f), 15.f);
  float e = __expf(2.f * xc);
  return (e - 1.f) * __builtin_amdgcn_rcpf(e + 1.f);
}

// ws layout (shorts): U[0,16384) V[16384,32768) M1[32768,49152)
//                     W1b[49152,65536) W2[65536,81920)
// b1p (f32[128]) at short offset 81920 (byte 163840).

// Straight conversions: U, V, W1b (= cols 128..255 of W1), W2.
__global__ void prep_cvt(const float* __restrict__ U_w, const float* __restrict__ V_w,
                         const float* __restrict__ W1, const float* __restrict__ W2,
                         short* __restrict__ ws) {
  int i = blockIdx.x * 256 + threadIdx.x;   // 65536 total
  if (i < 16384) {
    ws[i] = f2bf(U_w[i]);
  } else if (i < 32768) {
    ws[i] = f2bf(V_w[i - 16384]);
  } else if (i < 49152) {
    int j = i - 32768;                       // W1b[o][k] = W1[o][128+k]
    ws[i + 16384] = f2bf(W1[(j >> 7) * 256 + 128 + (j & 127)]);
  } else {
    int j = i - 49152;
    ws[i + 16384] = f2bf(W2[j]);
  }
}

// M1 = W1a @ P_w  (M1[o][c] = sum_k W1[o][k] * P_w[k][c]), bf16.
// b1p = b1 + W1a @ P_b, f32.
__global__ void prep_mm(const float* __restrict__ W1, const float* __restrict__ P_w,
                        const float* __restrict__ P_b, const float* __restrict__ b1,
                        short* __restrict__ ws) {
  int i = blockIdx.x * 256 + threadIdx.x;   // 16384 total
  int o = i >> 7, k = i & 127;
  const float* wrow = W1 + o * 256;         // W1a row o
  const float* pcol = P_w + k;
  float a0 = 0.f, a1 = 0.f, a2 = 0.f, a3 = 0.f;
#pragma unroll
  for (int c = 0; c < 128; c += 4) {
    a0 += wrow[c]     * pcol[c * 128];
    a1 += wrow[c + 1] * pcol[(c + 1) * 128];
    a2 += wrow[c + 2] * pcol[(c + 2) * 128];
    a3 += wrow[c + 3] * pcol[(c + 3) * 128];
  }
  ws[32768 + i] = f2bf((a0 + a1) + (a2 + a3));
  if (i < 128) {
    const float* wr = W1 + i * 256;
    float b = b1[i];
    for (int c = 0; c < 128; c++) b += wr[c] * P_b[c];
    ((float*)(ws + 81920))[i] = b;
  }
}

// Block = 64 edges. 4 waves split N (2 n-tiles each). 2 LDS buffers -> 4 blocks/CU.
//   bufA: Vsrc -> t -> h1       bufB: Vdst -> Ea
// Stage 2 (pooled) folded into stage 3 via M1 = W1a@P.
// Stage 1 tiled per-m (16 acc regs transient; t packed bf16 in 16 regs) so the
// unified RF never locks 64 AGPRs -> no scratch at launch_bounds(256,4).
// E loaded coalesced+nontemporal during stage-1 m=2 (latency hidden), committed
// to bufB (leaky+bf16) after the stage-1 barrier.
__global__ __launch_bounds__(256, 4) void fused_kernel(
    const float* __restrict__ V, const float* __restrict__ E,
    const int* __restrict__ src, const int* __restrict__ dst,
    const short* __restrict__ wbf,
    const float* __restrict__ b2, float* __restrict__ out) {
  __shared__ short bufA[64][136];
  __shared__ short bufB[64][136];

  const int tid  = threadIdx.x;
  const int lane = tid & 63;
  const int wave = tid >> 6;
  const int l15  = lane & 15;
  const int quad = lane >> 4;
  const int eb   = blockIdx.x * 64;
  const int n0   = wave * 2;            // this wave's first n-tile

  const short* wU   = wbf;
  const short* wV   = wbf + 16384;
  const short* wM1  = wbf + 32768;
  const short* wW1b = wbf + 49152;
  const short* wW2  = wbf + 65536;
  const float* b1p  = (const float*)(wbf + 81920);

  // biases for this wave's output columns
  float b1v[2], b2v[2];
#pragma unroll
  for (int n = 0; n < 2; n++) {
    int c = (n0 + n) * 16 + l15;
    b1v[n] = b1p[c]; b2v[n] = b2[c];
  }

  // ---------- staging: gather V[src], V[dst] -> LDS bf16 ----------
  for (int i = tid; i < 2048; i += 256) {   // 64 rows * 32 float4-chunks
    int row = i >> 5;
    int ch  = i & 31;
    int e   = eb + row;
    int s = src[e], d = dst[e];
    float4v vs = *((const float4v*)(V + (size_t)s * 128) + ch);
    float4v vd = *((const float4v*)(V + (size_t)d * 128) + ch);
    short4v ps = {f2bf(vs[0]), f2bf(vs[1]), f2bf(vs[2]), f2bf(vs[3])};
    short4v pd = {f2bf(vd[0]), f2bf(vd[1]), f2bf(vd[2]), f2bf(vd[3])};
    *(short4v*)&bufA[row][ch * 4] = ps;
    *(short4v*)&bufB[row][ch * 4] = pd;
  }
  __syncthreads();

  // ---------- stage 1: t = tanh((Vs@U^T)*(Vd@Vw^T)), tiled per m ----------
  short8 tpk[4];      // packed bf16 t, 4 regs per m-tile
  float4v ef[8];      // E prefetch (issued during m==2)
#pragma unroll
  for (int m = 0; m < 4; m++) {
    float4v accS[2] = {(float4v){0.f,0.f,0.f,0.f}, (float4v){0.f,0.f,0.f,0.f}};
    float4v accD[2] = {(float4v){0.f,0.f,0.f,0.f}, (float4v){0.f,0.f,0.f,0.f}};
#pragma unroll
    for (int kk = 0; kk < 4; kk++) {
      short8 bU[2], bV[2];
#pragma unroll
      for (int n = 0; n < 2; n++) {
        const int off = ((n0 + n) * 16 + l15) * 128 + kk * 32 + quad * 8;
        bU[n] = *(const short8*)(wU + off);
        bV[n] = *(const short8*)(wV + off);
      }
      short8 aS = *(const short8*)&bufA[m * 16 + l15][kk * 32 + quad * 8];
      short8 aD = *(const short8*)&bufB[m * 16 + l15][kk * 32 + quad * 8];
#pragma unroll
      for (int n = 0; n < 2; n++) {
        accS[n] = __builtin_amdgcn_mfma_f32_16x16x32_bf16(aS, bU[n], accS[n], 0, 0, 0);
        accD[n] = __builtin_amdgcn_mfma_f32_16x16x32_bf16(aD, bV[n], accD[n], 0, 0, 0);
      }
    }
    if (m == 2) {
      // coalesced nontemporal E loads; latency hidden under m=2 tanh + m=3 MFMAs
#pragma unroll
      for (int i = 0; i < 8; i++) {
        int idx = tid + (i << 8);
        int row = idx >> 5;
        int ch  = idx & 31;
        ef[i] = __builtin_nontemporal_load(
            (const float4v*)(E + (size_t)(eb + row) * 128) + ch);
      }
    }
    short tv[8];
#pragma unroll
    for (int n = 0; n < 2; n++)
#pragma unroll
      for (int r = 0; r < 4; r++)
        tv[n * 4 + r] = f2bf(fast_tanh(accS[n][r] * accD[n][r]));
    tpk[m] = (short8){tv[0], tv[1], tv[2], tv[3], tv[4], tv[5], tv[6], tv[7]};
  }
  __syncthreads();   // all stage-1 LDS reads done; bufA and bufB both free

  // t -> bufA (transpose through LDS); Ea -> bufB
#pragma unroll
  for (int m = 0; m < 4; m++)
#pragma unroll
    for (int n = 0; n < 2; n++)
#pragma unroll
      for (int r = 0; r < 4; r++)
        bufA[m * 16 + quad * 4 + r][(n0 + n) * 16 + l15] = tpk[m][n * 4 + r];
#pragma unroll
  for (int i = 0; i < 8; i++) {
    int idx = tid + (i << 8);
    int row = idx >> 5;
    int ch  = idx & 31;
    float4v x = ef[i];
    float e0 = x[0] > 0.f ? x[0] : 0.01f * x[0];
    float e1 = x[1] > 0.f ? x[1] : 0.01f * x[1];
    float e2 = x[2] > 0.f ? x[2] : 0.01f * x[2];
    float e3 = x[3] > 0.f ? x[3] : 0.01f * x[3];
    *(short4v*)&bufB[row][ch * 4] = (short4v){f2bf(e0), f2bf(e1), f2bf(e2), f2bf(e3)};
  }
  __syncthreads();

  // ---------- stage 3': h1 = relu(t @ M1^T + Ea @ W1b^T + b1') ----------
  float4v accH[4][2];
#pragma unroll
  for (int m = 0; m < 4; m++)
#pragma unroll
    for (int n = 0; n < 2; n++) accH[m][n] = (float4v){0.f, 0.f, 0.f, 0.f};
#pragma unroll
  for (int kk = 0; kk < 4; kk++) {   // K-half A: t @ M1
    short8 bM[2];
#pragma unroll
    for (int n = 0; n < 2; n++)
      bM[n] = *(const short8*)(wM1 + ((n0 + n) * 16 + l15) * 128 + kk * 32 + quad * 8);
#pragma unroll
    for (int m = 0; m < 4; m++) {
      short8 a = *(const short8*)&bufA[m * 16 + l15][kk * 32 + quad * 8];
#pragma unroll
      for (int n = 0; n < 2; n++)
        accH[m][n] = __builtin_amdgcn_mfma_f32_16x16x32_bf16(a, bM[n], accH[m][n], 0, 0, 0);
    }
  }
#pragma unroll
  for (int kk = 0; kk < 4; kk++) {   // K-half B: Ea @ W1b
    short8 bW[2];
#pragma unroll
    for (int n = 0; n < 2; n++)
      bW[n] = *(const short8*)(wW1b + ((n0 + n) * 16 + l15) * 128 + kk * 32 + quad * 8);
#pragma unroll
    for (int m = 0; m < 4; m++) {
      short8 a = *(const short8*)&bufB[m * 16 + l15][kk * 32 + quad * 8];
#pragma unroll
      for (int n = 0; n < 2; n++)
        accH[m][n] = __builtin_amdgcn_mfma_f32_16x16x32_bf16(a, bW[n], accH[m][n], 0, 0, 0);
    }
  }
  __syncthreads();   // all stage-3' LDS reads done; bufA free

  // h1 -> bufA
#pragma unroll
  for (int m = 0; m < 4; m++)
#pragma unroll
    for (int n = 0; n < 2; n++)
#pragma unroll
      for (int r = 0; r < 4; r++) {
        float v = fmaxf(accH[m][n][r] + b1v[n], 0.f);
        bufA[m * 16 + quad * 4 + r][(n0 + n) * 16 + l15] = f2bf(v);
      }
  __syncthreads();

  // ---------- stage 4: out = relu(h1 @ W2^T + b2) -> global ----------
  {
    float4v accO[4][2];
#pragma unroll
    for (int m = 0; m < 4; m++)
#pragma unroll
      for (int n = 0; n < 2; n++) accO[m][n] = (float4v){0.f, 0.f, 0.f, 0.f};
#pragma unroll
    for (int kk = 0; kk < 4; kk++) {
      short8 bW[2];
#pragma unroll
      for (int n = 0; n < 2; n++)
        bW[n] = *(const short8*)(wW2 + ((n0 + n) * 16 + l15) * 128 + kk * 32 + quad * 8);
#pragma unroll
      for (int m = 0; m < 4; m++) {
        short8 a = *(const short8*)&bufA[m * 16 + l15][kk * 32 + quad * 8];
#pragma unroll
        for (int n = 0; n < 2; n++)
          accO[m][n] = __builtin_amdgcn_mfma_f32_16x16x32_bf16(a, bW[n], accO[m][n], 0, 0, 0);
      }
    }
#pragma unroll
    for (int m = 0; m < 4; m++)
#pragma unroll
      for (int n = 0; n < 2; n++)
#pragma unroll
        for (int r = 0; r < 4; r++) {
          float v = fmaxf(accO[m][n][r] + b2v[n], 0.f);
          __builtin_nontemporal_store(
              v, out + (size_t)(eb + m * 16 + quad * 4 + r) * 128 + (n0 + n) * 16 + l15);
        }
  }
}

extern "C" void kernel_launch(void* const* d_in, const int* in_sizes, int n_in,
                              void* d_out, int out_size, void* d_ws, size_t ws_size,
                              hipStream_t stream) {
  const float* V   = (const float*)d_in[0];
  const float* E   = (const float*)d_in[1];
  const int*   src = (const int*)d_in[2];
  const int*   dst = (const int*)d_in[3];
  const float* U_w = (const float*)d_in[4];
  const float* V_w = (const float*)d_in[5];
  const float* P_w = (const float*)d_in[6];
  const float* P_b = (const float*)d_in[7];
  const float* W1  = (const float*)d_in[8];
  const float* b1  = (const float*)d_in[9];
  const float* W2  = (const float*)d_in[10];
  const float* b2  = (const float*)d_in[11];
  short* ws = (short*)d_ws;

  hipLaunchKernelGGL(prep_cvt, dim3(256), dim3(256), 0, stream, U_w, V_w, W1, W2, ws);
  hipLaunchKernelGGL(prep_mm, dim3(64), dim3(256), 0, stream, W1, P_w, P_b, b1, ws);
  hipLaunchKernelGGL(fused_kernel, dim3(N_EDGES / 64), dim3(256), 0, stream,
                     V, E, src, dst, ws, b2, (float*)d_out);
}